// Round 1
// baseline (437.564 us; speedup 1.0000x reference)
//
#include <hip/hip_runtime.h>
#include <hip/hip_bf16.h>
#include <cstdint>
#include <cstddef>

#define KDIM 4096   // out features
#define NDIM 4096   // in features (contraction dim)
#define NGRP 32
#define GSZ  128
#define MDIM 8192   // 4 * 2048 rows of x

typedef unsigned short ushort_t;
typedef float f32x4 __attribute__((ext_vector_type(4)));
typedef __bf16 bf16x8 __attribute__((ext_vector_type(8)));
typedef unsigned short u16x8 __attribute__((ext_vector_type(8)));
typedef int i32x4 __attribute__((ext_vector_type(4)));

// RTNE float -> bf16 (no NaN handling needed; inputs are bounded)
__device__ __forceinline__ ushort_t f2bf(float f) {
    union { float f; unsigned u; } v; v.f = f;
    unsigned r = v.u + 0x7FFFu + ((v.u >> 16) & 1u);
    return (ushort_t)(r >> 16);
}

__device__ __forceinline__ void gload_lds16(const void* g, void* l) {
    __builtin_amdgcn_global_load_lds(
        (const __attribute__((address_space(1))) unsigned int*)g,
        (__attribute__((address_space(3))) unsigned int*)l,
        16, 0, 0);
}

// ---------------- Pass 1a: dequantize W -> bf16 [K, N] ----------------
__global__ __launch_bounds__(256) void dq_w_kernel(
    const int* __restrict__ Wq, const float* __restrict__ scales,
    const float* __restrict__ zeros, const int* __restrict__ mask,
    const float* __restrict__ scale2, ushort_t* __restrict__ Wb) {
    int gid = blockIdx.x * 256 + threadIdx.x;   // one thread per 8 elems
    int e0 = gid * 8;                            // < 16,777,216
    int k = e0 >> 12;                            // row
    int n = e0 & (NDIM - 1);                     // col
    int g = n >> 7;                              // group (8 elems same group)
    float ss = scales[k * NGRP + g] * scale2[k];
    float z  = zeros[k * NGRP + g];
    i32x4 q0 = *(const i32x4*)(Wq + e0);
    i32x4 q1 = *(const i32x4*)(Wq + e0 + 4);
    i32x4 m0 = *(const i32x4*)(mask + e0);
    i32x4 m1 = *(const i32x4*)(mask + e0 + 4);
    u16x8 r;
#pragma unroll
    for (int i = 0; i < 4; ++i) {
        float f = ((float)q0[i] - z) * ss * (float)m0[i];
        r[i] = f2bf(f);
    }
#pragma unroll
    for (int i = 0; i < 4; ++i) {
        float f = ((float)q1[i] - z) * ss * (float)m1[i];
        r[4 + i] = f2bf(f);
    }
    *(u16x8*)(Wb + e0) = r;
}

// ---------------- Pass 1b: convert x fp32 -> bf16 [M, N] ----------------
__global__ __launch_bounds__(256) void cvt_x_kernel(
    const float* __restrict__ x, ushort_t* __restrict__ Xb) {
    int gid = blockIdx.x * 256 + threadIdx.x;   // one thread per 8 elems
    size_t e0 = (size_t)gid * 8;
    f32x4 a = *(const f32x4*)(x + e0);
    f32x4 b = *(const f32x4*)(x + e0 + 4);
    u16x8 r;
#pragma unroll
    for (int i = 0; i < 4; ++i) r[i] = f2bf(a[i]);
#pragma unroll
    for (int i = 0; i < 4; ++i) r[4 + i] = f2bf(b[i]);
    *(u16x8*)(Xb + e0) = r;
}

// ---------------- Pass 2: bf16 GEMM  out[m][k] = sum_n Xb[m][n]*Wb[k][n] + bias[k]
// 128x128 tile, BK=64, 256 threads (4 waves, 2x2), mfma_f32_16x16x32_bf16.
__global__ __launch_bounds__(256) void gemm_bt_kernel(
    const ushort_t* __restrict__ Xb, const ushort_t* __restrict__ Wb,
    const float* __restrict__ bias, float* __restrict__ out) {
    __shared__ ushort_t As[128 * 64];
    __shared__ ushort_t Bs[128 * 64];

    const int t    = threadIdx.x;
    const int lane = t & 63;
    const int wid  = t >> 6;
    const int wr   = wid >> 1;       // wave row (0..1)
    const int wc   = wid & 1;        // wave col (0..1)
    const int m0   = blockIdx.y * 128;
    const int n0   = blockIdx.x * 128;

    const int fr    = lane & 15;     // fragment row/col within 16
    const int khalf = lane >> 4;     // 0..3 -> k-subchunk of 8

    f32x4 acc[4][4];
#pragma unroll
    for (int i = 0; i < 4; ++i)
#pragma unroll
        for (int j = 0; j < 4; ++j) {
            f32x4 z = {0.f, 0.f, 0.f, 0.f};
            acc[i][j] = z;
        }

    // staging: granule G = r*256 + t (16B each); row = G>>3, colg = G&7
    const int srow[4] = { (0 * 256 + t) >> 3, (1 * 256 + t) >> 3,
                          (2 * 256 + t) >> 3, (3 * 256 + t) >> 3 };
    const int scol = (t & 7) * 8;                 // same for all rounds
    const int ldsbase = (t & 192) * 16;           // wave-uniform byte base

    for (int kt = 0; kt < NDIM / 64; ++kt) {
        const int kbase = kt * 64;
#pragma unroll
        for (int r = 0; r < 4; ++r) {
            const ushort_t* ga = Xb + (size_t)(m0 + srow[r]) * NDIM + kbase + scol;
            const ushort_t* gb = Wb + (size_t)(n0 + srow[r]) * NDIM + kbase + scol;
            int lo = r * 256 * 16 + ldsbase;      // linear byte offset
            gload_lds16(ga, (char*)As + lo);
            gload_lds16(gb, (char*)Bs + lo);
        }
        __syncthreads();   // compiler drains vmcnt before s_barrier
#pragma unroll
        for (int kk = 0; kk < 2; ++kk) {
            bf16x8 af[4], bv[4];
#pragma unroll
            for (int i = 0; i < 4; ++i)
                af[i] = *(const bf16x8*)&As[(wr * 64 + i * 16 + fr) * 64 + kk * 32 + khalf * 8];
#pragma unroll
            for (int i = 0; i < 4; ++i)
                bv[i] = *(const bf16x8*)&Bs[(wc * 64 + i * 16 + fr) * 64 + kk * 32 + khalf * 8];
#pragma unroll
            for (int i = 0; i < 4; ++i)
#pragma unroll
                for (int j = 0; j < 4; ++j)
                    acc[i][j] = __builtin_amdgcn_mfma_f32_16x16x32_bf16(
                        af[i], bv[j], acc[i][j], 0, 0, 0);
        }
        __syncthreads();
    }

    // epilogue: C/D layout col = lane&15, row = (lane>>4)*4 + q
    const int ccol0 = n0 + wc * 64 + fr;
    const int crow0 = m0 + wr * 64 + khalf * 4;
    float bvv[4];
#pragma unroll
    for (int j = 0; j < 4; ++j) bvv[j] = bias[ccol0 + j * 16];
#pragma unroll
    for (int i = 0; i < 4; ++i)
#pragma unroll
        for (int j = 0; j < 4; ++j)
#pragma unroll
            for (int q = 0; q < 4; ++q)
                out[(size_t)(crow0 + i * 16 + q) * KDIM + ccol0 + j * 16] =
                    acc[i][j][q] + bvv[j];
}

// ---------------- Fallback (only if ws too small): naive fused ----------------
__global__ __launch_bounds__(256) void naive_kernel(
    const float* __restrict__ x, const int* __restrict__ Wq,
    const float* __restrict__ scales, const float* __restrict__ zeros,
    const int* __restrict__ mask, const float* __restrict__ scale2,
    const float* __restrict__ bias, float* __restrict__ out) {
    size_t o = (size_t)blockIdx.x * 256 + threadIdx.x;
    int m = (int)(o >> 12);
    int k = (int)(o & (KDIM - 1));
    const float* xr = x + (size_t)m * NDIM;
    const int* wr = Wq + (size_t)k * NDIM;
    const int* mr = mask + (size_t)k * NDIM;
    float s2 = scale2[k];
    float acc = 0.f;
    for (int g = 0; g < NGRP; ++g) {
        float ss = scales[k * NGRP + g] * s2;
        float z = zeros[k * NGRP + g];
        for (int n = g * GSZ; n < (g + 1) * GSZ; ++n) {
            float w = ((float)wr[n] - z) * ss * (float)mr[n];
            acc += xr[n] * w;
        }
    }
    out[o] = acc + bias[k];
}

extern "C" void kernel_launch(void* const* d_in, const int* in_sizes, int n_in,
                              void* d_out, int out_size, void* d_ws, size_t ws_size,
                              hipStream_t stream) {
    const float* x      = (const float*)d_in[0];
    const int*   Wq     = (const int*)d_in[1];
    const float* scales = (const float*)d_in[2];
    const float* zeros  = (const float*)d_in[3];
    const int*   mask   = (const int*)d_in[4];
    const float* scale2 = (const float*)d_in[5];
    const float* bias   = (const float*)d_in[6];
    float* out = (float*)d_out;

    const size_t needW = (size_t)KDIM * NDIM * sizeof(ushort_t);  // 32 MiB
    const size_t needX = (size_t)MDIM * NDIM * sizeof(ushort_t);  // 64 MiB

    if (ws_size >= needW + needX) {
        ushort_t* Wb = (ushort_t*)d_ws;
        ushort_t* Xb = (ushort_t*)((char*)d_ws + needW);
        hipLaunchKernelGGL(dq_w_kernel, dim3((KDIM * NDIM / 8) / 256), dim3(256),
                           0, stream, Wq, scales, zeros, mask, scale2, Wb);
        hipLaunchKernelGGL(cvt_x_kernel, dim3((MDIM * NDIM / 8) / 256), dim3(256),
                           0, stream, x, Xb);
        hipLaunchKernelGGL(gemm_bt_kernel, dim3(KDIM / 128, MDIM / 128), dim3(256),
                           0, stream, Xb, Wb, bias, out);
    } else {
        hipLaunchKernelGGL(naive_kernel, dim3((MDIM * KDIM) / 256), dim3(256),
                           0, stream, x, Wq, scales, zeros, mask, scale2, bias, out);
    }
}

// Round 2
// 316.133 us; speedup vs baseline: 1.3841x; 1.3841x over previous
//
#include <hip/hip_runtime.h>
#include <hip/hip_bf16.h>
#include <cstdint>
#include <cstddef>

#define KDIM 4096   // out features
#define NDIM 4096   // in features (contraction dim)
#define NGRP 32
#define GSZ  128
#define MDIM 8192   // 4 * 2048 rows of x
#define NT   (NDIM / 64)   // 64 K-tiles of BK=64

typedef unsigned short ushort_t;
typedef float f32x4 __attribute__((ext_vector_type(4)));
typedef __bf16 bf16x8 __attribute__((ext_vector_type(8)));
typedef unsigned short u16x8 __attribute__((ext_vector_type(8)));
typedef int i32x4 __attribute__((ext_vector_type(4)));

// RTNE float -> bf16
__device__ __forceinline__ ushort_t f2bf(float f) {
    union { float f; unsigned u; } v; v.f = f;
    unsigned r = v.u + 0x7FFFu + ((v.u >> 16) & 1u);
    return (ushort_t)(r >> 16);
}

__device__ __forceinline__ void gload_lds16(const void* g, void* l) {
    __builtin_amdgcn_global_load_lds(
        (const __attribute__((address_space(1))) unsigned int*)g,
        (__attribute__((address_space(3))) unsigned int*)l,
        16, 0, 0);
}

// ---------------- Pass 1a: dequantize W -> bf16 [K, N] ----------------
__global__ __launch_bounds__(256) void dq_w_kernel(
    const int* __restrict__ Wq, const float* __restrict__ scales,
    const float* __restrict__ zeros, const int* __restrict__ mask,
    const float* __restrict__ scale2, ushort_t* __restrict__ Wb) {
    int gid = blockIdx.x * 256 + threadIdx.x;
    int e0 = gid * 8;
    int k = e0 >> 12;
    int n = e0 & (NDIM - 1);
    int g = n >> 7;
    float ss = scales[k * NGRP + g] * scale2[k];
    float z  = zeros[k * NGRP + g];
    i32x4 q0 = *(const i32x4*)(Wq + e0);
    i32x4 q1 = *(const i32x4*)(Wq + e0 + 4);
    i32x4 m0 = *(const i32x4*)(mask + e0);
    i32x4 m1 = *(const i32x4*)(mask + e0 + 4);
    u16x8 r;
#pragma unroll
    for (int i = 0; i < 4; ++i) r[i]     = f2bf(((float)q0[i] - z) * ss * (float)m0[i]);
#pragma unroll
    for (int i = 0; i < 4; ++i) r[4 + i] = f2bf(((float)q1[i] - z) * ss * (float)m1[i]);
    *(u16x8*)(Wb + e0) = r;
}

// ---------------- Pass 1b: convert x fp32 -> bf16 [M, N] ----------------
__global__ __launch_bounds__(256) void cvt_x_kernel(
    const float* __restrict__ x, ushort_t* __restrict__ Xb) {
    int gid = blockIdx.x * 256 + threadIdx.x;
    size_t e0 = (size_t)gid * 8;
    f32x4 a = *(const f32x4*)(x + e0);
    f32x4 b = *(const f32x4*)(x + e0 + 4);
    u16x8 r;
#pragma unroll
    for (int i = 0; i < 4; ++i) r[i] = f2bf(a[i]);
#pragma unroll
    for (int i = 0; i < 4; ++i) r[4 + i] = f2bf(b[i]);
    *(u16x8*)(Xb + e0) = r;
}

// ---------------- Pass 2: 256x256-tile 8-phase bf16 GEMM ----------------
// out[m][k] = sum_n Xb[m][n] * Wb[k][n] + bias[k]
// 512 threads = 8 waves (2 Mx4 N). BK=64. LDS: 2 slots x {A0,A1,B0,B1} halves
// of [128][64] bf16 (16 KB each) = 128 KiB. Swizzle: chunk ^= (row&7), applied
// to the pre-swizzled GLOBAL source (linear global_load_lds dest) and to the
// ds_read address (both-sides involution).

#define LDS_SLOT 65536
#define LDS_A0   0
#define LDS_A1   16384
#define LDS_B0   32768
#define LDS_B1   49152

#define STAGE(ldsHalf, gbase) do { \
    gload_lds16((gbase) + goff0, (ldsHalf) + ldsoff0); \
    gload_lds16((gbase) + goff1, (ldsHalf) + ldsoff1); } while (0)

#define MFMA16(QM, QN) do { \
    acc[(QM)*4+0][(QN)*2+0] = __builtin_amdgcn_mfma_f32_16x16x32_bf16(a00, b00, acc[(QM)*4+0][(QN)*2+0], 0,0,0); \
    acc[(QM)*4+1][(QN)*2+0] = __builtin_amdgcn_mfma_f32_16x16x32_bf16(a10, b00, acc[(QM)*4+1][(QN)*2+0], 0,0,0); \
    acc[(QM)*4+2][(QN)*2+0] = __builtin_amdgcn_mfma_f32_16x16x32_bf16(a20, b00, acc[(QM)*4+2][(QN)*2+0], 0,0,0); \
    acc[(QM)*4+3][(QN)*2+0] = __builtin_amdgcn_mfma_f32_16x16x32_bf16(a30, b00, acc[(QM)*4+3][(QN)*2+0], 0,0,0); \
    acc[(QM)*4+0][(QN)*2+1] = __builtin_amdgcn_mfma_f32_16x16x32_bf16(a00, b10, acc[(QM)*4+0][(QN)*2+1], 0,0,0); \
    acc[(QM)*4+1][(QN)*2+1] = __builtin_amdgcn_mfma_f32_16x16x32_bf16(a10, b10, acc[(QM)*4+1][(QN)*2+1], 0,0,0); \
    acc[(QM)*4+2][(QN)*2+1] = __builtin_amdgcn_mfma_f32_16x16x32_bf16(a20, b10, acc[(QM)*4+2][(QN)*2+1], 0,0,0); \
    acc[(QM)*4+3][(QN)*2+1] = __builtin_amdgcn_mfma_f32_16x16x32_bf16(a30, b10, acc[(QM)*4+3][(QN)*2+1], 0,0,0); \
    acc[(QM)*4+0][(QN)*2+0] = __builtin_amdgcn_mfma_f32_16x16x32_bf16(a01, b01, acc[(QM)*4+0][(QN)*2+0], 0,0,0); \
    acc[(QM)*4+1][(QN)*2+0] = __builtin_amdgcn_mfma_f32_16x16x32_bf16(a11, b01, acc[(QM)*4+1][(QN)*2+0], 0,0,0); \
    acc[(QM)*4+2][(QN)*2+0] = __builtin_amdgcn_mfma_f32_16x16x32_bf16(a21, b01, acc[(QM)*4+2][(QN)*2+0], 0,0,0); \
    acc[(QM)*4+3][(QN)*2+0] = __builtin_amdgcn_mfma_f32_16x16x32_bf16(a31, b01, acc[(QM)*4+3][(QN)*2+0], 0,0,0); \
    acc[(QM)*4+0][(QN)*2+1] = __builtin_amdgcn_mfma_f32_16x16x32_bf16(a01, b11, acc[(QM)*4+0][(QN)*2+1], 0,0,0); \
    acc[(QM)*4+1][(QN)*2+1] = __builtin_amdgcn_mfma_f32_16x16x32_bf16(a11, b11, acc[(QM)*4+1][(QN)*2+1], 0,0,0); \
    acc[(QM)*4+2][(QN)*2+1] = __builtin_amdgcn_mfma_f32_16x16x32_bf16(a21, b11, acc[(QM)*4+2][(QN)*2+1], 0,0,0); \
    acc[(QM)*4+3][(QN)*2+1] = __builtin_amdgcn_mfma_f32_16x16x32_bf16(a31, b11, acc[(QM)*4+3][(QN)*2+1], 0,0,0); \
} while (0)

// Phase: ds_read 12 fragments (slot S, A-half QM, B-half QN) || stage issue ->
// barrier -> lgkmcnt(0) -> setprio(1) 16xMFMA setprio(0). End barrier outside.
#define PHASE(S, QM, QN, STAGECODE) do { \
    const char* Ab_ = lds + (S)*LDS_SLOT + (QM)*16384 + rowA; \
    const char* Bb_ = lds + (S)*LDS_SLOT + 32768 + (QN)*16384 + rowB; \
    bf16x8 a00 = *(const bf16x8*)(Ab_ + 0*2048 + cb0); \
    bf16x8 a10 = *(const bf16x8*)(Ab_ + 1*2048 + cb0); \
    bf16x8 a20 = *(const bf16x8*)(Ab_ + 2*2048 + cb0); \
    bf16x8 a30 = *(const bf16x8*)(Ab_ + 3*2048 + cb0); \
    bf16x8 a01 = *(const bf16x8*)(Ab_ + 0*2048 + cb1); \
    bf16x8 a11 = *(const bf16x8*)(Ab_ + 1*2048 + cb1); \
    bf16x8 a21 = *(const bf16x8*)(Ab_ + 2*2048 + cb1); \
    bf16x8 a31 = *(const bf16x8*)(Ab_ + 3*2048 + cb1); \
    bf16x8 b00 = *(const bf16x8*)(Bb_ + 0*2048 + cb0); \
    bf16x8 b10 = *(const bf16x8*)(Bb_ + 1*2048 + cb0); \
    bf16x8 b01 = *(const bf16x8*)(Bb_ + 0*2048 + cb1); \
    bf16x8 b11 = *(const bf16x8*)(Bb_ + 1*2048 + cb1); \
    STAGECODE; \
    asm volatile("s_barrier" ::: "memory"); \
    asm volatile("s_waitcnt lgkmcnt(0)" ::: "memory"); \
    __builtin_amdgcn_sched_barrier(0); \
    __builtin_amdgcn_s_setprio(1); \
    MFMA16(QM, QN); \
    __builtin_amdgcn_s_setprio(0); \
} while (0)

#define BAR       asm volatile("s_barrier" ::: "memory")
#define VMCNT2    asm volatile("s_waitcnt vmcnt(2)" ::: "memory")

__global__ __launch_bounds__(512, 2) void gemm8p_kernel(
    const ushort_t* __restrict__ Xb, const ushort_t* __restrict__ Wb,
    const float* __restrict__ bias, float* __restrict__ out) {
    extern __shared__ char lds[];

    const int tid   = threadIdx.x;
    const int lane  = tid & 63;
    const int wid   = tid >> 6;      // 0..7
    const int wm    = wid >> 2;      // 0..1  (M sub-block within each half)
    const int wn    = wid & 3;       // 0..3  (N sub-block within each half)
    const int fr    = lane & 15;
    const int khalf = lane >> 4;     // 0..3

    // T1: bijective XCD swizzle (512 % 8 == 0)
    const int orig  = blockIdx.x;
    const int wgid  = ((orig & 7) << 6) | (orig >> 3);
    const int ntile = wgid & 15;     // 16 N-tiles
    const int mtile = wgid >> 4;     // 32 M-tiles
    const int m0 = mtile << 8;
    const int n0 = ntile << 8;

    // stage addressing: granule g = l*512 + tid; LDS linear; global pre-swizzled
    const int g0 = tid, g1 = 512 + tid;
    const size_t goff0 = (size_t)(g0 >> 3) * NDIM + (size_t)((((g0 & 7) ^ ((g0 >> 3) & 7))) << 3);
    const size_t goff1 = (size_t)(g1 >> 3) * NDIM + (size_t)((((g1 & 7) ^ ((g1 >> 3) & 7))) << 3);
    const int ldsoff0 = (wid << 10);          // wave-uniform base, load 0
    const int ldsoff1 = 8192 + (wid << 10);   // load 1

    // fragment read offsets (bytes within a [128][64] bf16 half-buffer)
    const int rowA = ((wm << 6) + fr) << 7;               // (wm*64+fr)*128
    const int rowB = ((wn << 5) + fr) << 7;               // (wn*32+fr)*128
    const int cb0  = ((khalf)     ^ (fr & 7)) << 4;       // kk=0 chunk (swizzled)
    const int cb1  = ((4 + khalf) ^ (fr & 7)) << 4;       // kk=1 chunk

    f32x4 acc[8][4];
#pragma unroll
    for (int i = 0; i < 8; ++i)
#pragma unroll
        for (int j = 0; j < 4; ++j) { f32x4 z = {0.f,0.f,0.f,0.f}; acc[i][j] = z; }

    const ushort_t* Xrow0 = Xb + (size_t)m0 * NDIM;
    const ushort_t* Xrow1 = Xb + (size_t)(m0 + 128) * NDIM;
    const ushort_t* Wrow0 = Wb + (size_t)n0 * NDIM;
    const ushort_t* Wrow1 = Wb + (size_t)(n0 + 128) * NDIM;

    // Prologue stream: A0[0],B0[0],A1[0],B1[0],A0[1],B0[1]; leave newest
    // half-tile (B0[1]) in flight — matches steady-state boundary condition.
    STAGE(lds + 0*LDS_SLOT + LDS_A0, Xrow0 + 0);
    STAGE(lds + 0*LDS_SLOT + LDS_B0, Wrow0 + 0);
    STAGE(lds + 0*LDS_SLOT + LDS_A1, Xrow1 + 0);
    STAGE(lds + 0*LDS_SLOT + LDS_B1, Wrow1 + 0);
    STAGE(lds + 1*LDS_SLOT + LDS_A0, Xrow0 + 64);
    STAGE(lds + 1*LDS_SLOT + LDS_B0, Wrow0 + 64);
    VMCNT2;
    BAR;

    // Main loop: 2 K-tiles (8 phases) per iteration, compile-time slots.
    // Stage schedule per K-tile t (slot S): ph0 A1[t+1]->S^1, ph1 B1[t+1]->S^1,
    // ph2 A0[t+2]->S, ph3 B0[t+2]->S.  vmcnt(2) only at K-tile boundaries.
#pragma unroll 1
    for (int kt2 = 0; kt2 < NT / 2; ++kt2) {
        const int te = 2 * kt2, to = te + 1;
        PHASE(0, 0, 0, if (te + 1 < NT) STAGE(lds + 1*LDS_SLOT + LDS_A1, Xrow1 + (te+1)*64)); BAR;
        PHASE(0, 0, 1, if (te + 1 < NT) STAGE(lds + 1*LDS_SLOT + LDS_B1, Wrow1 + (te+1)*64)); BAR;
        PHASE(0, 1, 0, if (te + 2 < NT) STAGE(lds + 0*LDS_SLOT + LDS_A0, Xrow0 + (te+2)*64)); BAR;
        PHASE(0, 1, 1, if (te + 2 < NT) STAGE(lds + 0*LDS_SLOT + LDS_B0, Wrow0 + (te+2)*64)); VMCNT2; BAR;
        PHASE(1, 0, 0, if (to + 1 < NT) STAGE(lds + 0*LDS_SLOT + LDS_A1, Xrow1 + (to+1)*64)); BAR;
        PHASE(1, 0, 1, if (to + 1 < NT) STAGE(lds + 0*LDS_SLOT + LDS_B1, Wrow1 + (to+1)*64)); BAR;
        PHASE(1, 1, 0, if (to + 2 < NT) STAGE(lds + 1*LDS_SLOT + LDS_A0, Xrow0 + (to+2)*64)); BAR;
        PHASE(1, 1, 1, if (to + 2 < NT) STAGE(lds + 1*LDS_SLOT + LDS_B0, Wrow0 + (to+2)*64)); VMCNT2; BAR;
    }

    // Epilogue: C/D layout col=lane&15, row=(lane>>4)*4+reg.
    // row(i) = m0 + (i>>2)*128 + wm*64 + (i&3)*16 + khalf*4 + q
    // col(j) = n0 + (j>>1)*128 + wn*32 + (j&1)*16 + fr
    float bv[4];
#pragma unroll
    for (int j = 0; j < 4; ++j)
        bv[j] = bias[n0 + ((j >> 1) << 7) + (wn << 5) + ((j & 1) << 4) + fr];
#pragma unroll
    for (int i = 0; i < 8; ++i) {
        const int row = m0 + ((i >> 2) << 7) + (wm << 6) + ((i & 3) << 4) + (khalf << 2);
#pragma unroll
        for (int j = 0; j < 4; ++j) {
            const int col = n0 + ((j >> 1) << 7) + (wn << 5) + ((j & 1) << 4) + fr;
#pragma unroll
            for (int q = 0; q < 4; ++q)
                out[(size_t)(row + q) * KDIM + col] = acc[i][j][q] + bv[j];
        }
    }
}

// ---------------- Fallback (only if ws too small): naive fused ----------------
__global__ __launch_bounds__(256) void naive_kernel(
    const float* __restrict__ x, const int* __restrict__ Wq,
    const float* __restrict__ scales, const float* __restrict__ zeros,
    const int* __restrict__ mask, const float* __restrict__ scale2,
    const float* __restrict__ bias, float* __restrict__ out) {
    size_t o = (size_t)blockIdx.x * 256 + threadIdx.x;
    int m = (int)(o >> 12);
    int k = (int)(o & (KDIM - 1));
    const float* xr = x + (size_t)m * NDIM;
    const int* wr = Wq + (size_t)k * NDIM;
    const int* mr = mask + (size_t)k * NDIM;
    float s2 = scale2[k];
    float acc = 0.f;
    for (int g = 0; g < NGRP; ++g) {
        float ss = scales[k * NGRP + g] * s2;
        float z = zeros[k * NGRP + g];
        for (int n = g * GSZ; n < (g + 1) * GSZ; ++n)
            acc += xr[n] * (((float)wr[n] - z) * ss * (float)mr[n]);
    }
    out[o] = acc + bias[k];
}

extern "C" void kernel_launch(void* const* d_in, const int* in_sizes, int n_in,
                              void* d_out, int out_size, void* d_ws, size_t ws_size,
                              hipStream_t stream) {
    const float* x      = (const float*)d_in[0];
    const int*   Wq     = (const int*)d_in[1];
    const float* scales = (const float*)d_in[2];
    const float* zeros  = (const float*)d_in[3];
    const int*   mask   = (const int*)d_in[4];
    const float* scale2 = (const float*)d_in[5];
    const float* bias   = (const float*)d_in[6];
    float* out = (float*)d_out;

    const size_t needW = (size_t)KDIM * NDIM * sizeof(ushort_t);  // 32 MiB
    const size_t needX = (size_t)MDIM * NDIM * sizeof(ushort_t);  // 64 MiB

    if (ws_size >= needW + needX) {
        ushort_t* Wb = (ushort_t*)d_ws;
        ushort_t* Xb = (ushort_t*)((char*)d_ws + needW);
        hipLaunchKernelGGL(dq_w_kernel, dim3((KDIM * NDIM / 8) / 256), dim3(256),
                           0, stream, Wq, scales, zeros, mask, scale2, Wb);
        hipLaunchKernelGGL(cvt_x_kernel, dim3((MDIM * NDIM / 8) / 256), dim3(256),
                           0, stream, x, Xb);
        hipFuncSetAttribute((const void*)gemm8p_kernel,
                            hipFuncAttributeMaxDynamicSharedMemorySize, 131072);
        hipLaunchKernelGGL(gemm8p_kernel, dim3((MDIM / 256) * (KDIM / 256)), dim3(512),
                           131072, stream, Xb, Wb, bias, out);
    } else {
        hipLaunchKernelGGL(naive_kernel, dim3((MDIM * KDIM) / 256), dim3(256),
                           0, stream, x, Wq, scales, zeros, mask, scale2, bias, out);
    }
}

// Round 3
// 288.426 us; speedup vs baseline: 1.5171x; 1.0961x over previous
//
#include <hip/hip_runtime.h>
#include <hip/hip_bf16.h>
#include <cstdint>
#include <cstddef>

#define KDIM 4096   // out features
#define NDIM 4096   // in features (contraction dim)
#define NGRP 32
#define GSZ  128
#define MDIM 8192   // 4 * 2048 rows of x
#define NT   (NDIM / 64)   // 64 K-tiles of BK=64

typedef unsigned short ushort_t;
typedef float f32x4 __attribute__((ext_vector_type(4)));
typedef __bf16 bf16x8 __attribute__((ext_vector_type(8)));
typedef unsigned short u16x8 __attribute__((ext_vector_type(8)));
typedef int i32x4 __attribute__((ext_vector_type(4)));

// RTNE float -> bf16
__device__ __forceinline__ ushort_t f2bf(float f) {
    union { float f; unsigned u; } v; v.f = f;
    unsigned r = v.u + 0x7FFFu + ((v.u >> 16) & 1u);
    return (ushort_t)(r >> 16);
}

__device__ __forceinline__ void gload_lds16(const void* g, void* l) {
    __builtin_amdgcn_global_load_lds(
        (const __attribute__((address_space(1))) unsigned int*)g,
        (__attribute__((address_space(3))) unsigned int*)l,
        16, 0, 0);
}

// ---------------- Pass 1a: dequantize W -> bf16 [K, N] ----------------
__global__ __launch_bounds__(256) void dq_w_kernel(
    const int* __restrict__ Wq, const float* __restrict__ scales,
    const float* __restrict__ zeros, const int* __restrict__ mask,
    const float* __restrict__ scale2, ushort_t* __restrict__ Wb) {
    int gid = blockIdx.x * 256 + threadIdx.x;
    int e0 = gid * 8;
    int k = e0 >> 12;
    int n = e0 & (NDIM - 1);
    int g = n >> 7;
    float ss = scales[k * NGRP + g] * scale2[k];
    float z  = zeros[k * NGRP + g];
    i32x4 q0 = *(const i32x4*)(Wq + e0);
    i32x4 q1 = *(const i32x4*)(Wq + e0 + 4);
    i32x4 m0 = *(const i32x4*)(mask + e0);
    i32x4 m1 = *(const i32x4*)(mask + e0 + 4);
    u16x8 r;
#pragma unroll
    for (int i = 0; i < 4; ++i) r[i]     = f2bf(((float)q0[i] - z) * ss * (float)m0[i]);
#pragma unroll
    for (int i = 0; i < 4; ++i) r[4 + i] = f2bf(((float)q1[i] - z) * ss * (float)m1[i]);
    *(u16x8*)(Wb + e0) = r;
}

// ---------------- Pass 1b: convert x fp32 -> bf16 [M, N] ----------------
__global__ __launch_bounds__(256) void cvt_x_kernel(
    const float* __restrict__ x, ushort_t* __restrict__ Xb) {
    int gid = blockIdx.x * 256 + threadIdx.x;
    size_t e0 = (size_t)gid * 8;
    f32x4 a = *(const f32x4*)(x + e0);
    f32x4 b = *(const f32x4*)(x + e0 + 4);
    u16x8 r;
#pragma unroll
    for (int i = 0; i < 4; ++i) r[i] = f2bf(a[i]);
#pragma unroll
    for (int i = 0; i < 4; ++i) r[4 + i] = f2bf(b[i]);
    *(u16x8*)(Xb + e0) = r;
}

// ---------------- Pass 2: 256x256-tile 8-phase bf16 GEMM ----------------
// out[m][k] = sum_n Xb[m][n] * Wb[k][n] + bias[k]
// 512 threads = 8 waves (2M x 4N). BK=64. LDS: 2 slots x {A0,A1,B0,B1} halves
// of [128][64] bf16 (16 KB each) = 128 KiB.
// Gray-code phase order (A0,B0)->(A1,B0)->(A1,B1)->(A0,B1) with register-
// cached fragments: 12/8/4/8 ds_read_b128 per phase (vs 12/12/12/12).
// Stage schedule per tile t: ph0 A0[t+1]->other slot; ph1 B0[t+2], ph2 A1[t+2],
// ph3 B1[t+2] -> own slot (each issued one phase after that half's last read).
// vmcnt(6) at tile boundaries = 3 half-tiles in flight (template formula).
// Last 2 tiles peeled: vmcnt(0) at the t=62 boundary (tail forcing), so the
// hot loop is statically guard-free.

#define LDS_SLOT 65536
#define LDS_A0   0
#define LDS_A1   16384
#define LDS_B0   32768
#define LDS_B1   49152

#define STAGE(ldsHalf, gbase) do { \
    gload_lds16((gbase) + goff0, (ldsHalf) + ldsoff0); \
    gload_lds16((gbase) + goff1, (ldsHalf) + ldsoff1); } while (0)

#define READ_A(S, QM) do { \
    const char* Ab_ = lds + (S)*LDS_SLOT + (QM)*16384 + rowA; \
    a00 = *(const bf16x8*)(Ab_ + 0*2048 + cb0); \
    a10 = *(const bf16x8*)(Ab_ + 1*2048 + cb0); \
    a20 = *(const bf16x8*)(Ab_ + 2*2048 + cb0); \
    a30 = *(const bf16x8*)(Ab_ + 3*2048 + cb0); \
    a01 = *(const bf16x8*)(Ab_ + 0*2048 + cb1); \
    a11 = *(const bf16x8*)(Ab_ + 1*2048 + cb1); \
    a21 = *(const bf16x8*)(Ab_ + 2*2048 + cb1); \
    a31 = *(const bf16x8*)(Ab_ + 3*2048 + cb1); \
} while (0)

#define READ_B(S, QN, B00, B10, B01, B11) do { \
    const char* Bb_ = lds + (S)*LDS_SLOT + 32768 + (QN)*16384 + rowB; \
    B00 = *(const bf16x8*)(Bb_ + 0*2048 + cb0); \
    B10 = *(const bf16x8*)(Bb_ + 1*2048 + cb0); \
    B01 = *(const bf16x8*)(Bb_ + 0*2048 + cb1); \
    B11 = *(const bf16x8*)(Bb_ + 1*2048 + cb1); \
} while (0)

#define MFMA16(QM, QN, B00, B10, B01, B11) do { \
    acc[(QM)*4+0][(QN)*2+0] = __builtin_amdgcn_mfma_f32_16x16x32_bf16(a00, B00, acc[(QM)*4+0][(QN)*2+0], 0,0,0); \
    acc[(QM)*4+1][(QN)*2+0] = __builtin_amdgcn_mfma_f32_16x16x32_bf16(a10, B00, acc[(QM)*4+1][(QN)*2+0], 0,0,0); \
    acc[(QM)*4+2][(QN)*2+0] = __builtin_amdgcn_mfma_f32_16x16x32_bf16(a20, B00, acc[(QM)*4+2][(QN)*2+0], 0,0,0); \
    acc[(QM)*4+3][(QN)*2+0] = __builtin_amdgcn_mfma_f32_16x16x32_bf16(a30, B00, acc[(QM)*4+3][(QN)*2+0], 0,0,0); \
    acc[(QM)*4+0][(QN)*2+1] = __builtin_amdgcn_mfma_f32_16x16x32_bf16(a00, B10, acc[(QM)*4+0][(QN)*2+1], 0,0,0); \
    acc[(QM)*4+1][(QN)*2+1] = __builtin_amdgcn_mfma_f32_16x16x32_bf16(a10, B10, acc[(QM)*4+1][(QN)*2+1], 0,0,0); \
    acc[(QM)*4+2][(QN)*2+1] = __builtin_amdgcn_mfma_f32_16x16x32_bf16(a20, B10, acc[(QM)*4+2][(QN)*2+1], 0,0,0); \
    acc[(QM)*4+3][(QN)*2+1] = __builtin_amdgcn_mfma_f32_16x16x32_bf16(a30, B10, acc[(QM)*4+3][(QN)*2+1], 0,0,0); \
    acc[(QM)*4+0][(QN)*2+0] = __builtin_amdgcn_mfma_f32_16x16x32_bf16(a01, B01, acc[(QM)*4+0][(QN)*2+0], 0,0,0); \
    acc[(QM)*4+1][(QN)*2+0] = __builtin_amdgcn_mfma_f32_16x16x32_bf16(a11, B01, acc[(QM)*4+1][(QN)*2+0], 0,0,0); \
    acc[(QM)*4+2][(QN)*2+0] = __builtin_amdgcn_mfma_f32_16x16x32_bf16(a21, B01, acc[(QM)*4+2][(QN)*2+0], 0,0,0); \
    acc[(QM)*4+3][(QN)*2+0] = __builtin_amdgcn_mfma_f32_16x16x32_bf16(a31, B01, acc[(QM)*4+3][(QN)*2+0], 0,0,0); \
    acc[(QM)*4+0][(QN)*2+1] = __builtin_amdgcn_mfma_f32_16x16x32_bf16(a01, B11, acc[(QM)*4+0][(QN)*2+1], 0,0,0); \
    acc[(QM)*4+1][(QN)*2+1] = __builtin_amdgcn_mfma_f32_16x16x32_bf16(a11, B11, acc[(QM)*4+1][(QN)*2+1], 0,0,0); \
    acc[(QM)*4+2][(QN)*2+1] = __builtin_amdgcn_mfma_f32_16x16x32_bf16(a21, B11, acc[(QM)*4+2][(QN)*2+1], 0,0,0); \
    acc[(QM)*4+3][(QN)*2+1] = __builtin_amdgcn_mfma_f32_16x16x32_bf16(a31, B11, acc[(QM)*4+3][(QN)*2+1], 0,0,0); \
} while (0)

#define PH_PRE do { \
    asm volatile("s_barrier" ::: "memory"); \
    asm volatile("s_waitcnt lgkmcnt(0)" ::: "memory"); \
    __builtin_amdgcn_sched_barrier(0); \
    __builtin_amdgcn_s_setprio(1); \
} while (0)
#define PH_POST do { \
    __builtin_amdgcn_s_setprio(0); \
    asm volatile("s_barrier" ::: "memory"); \
} while (0)

#define BAR    asm volatile("s_barrier" ::: "memory")
#define VMCNT6 asm volatile("s_waitcnt vmcnt(6)" ::: "memory")
#define VMCNT0 asm volatile("s_waitcnt vmcnt(0)" ::: "memory")

// One K-tile (4 Gray-code phases). BND sits after ph3's MFMA, before end-bar.
#define TILE(S, ST0, ST1, ST2, ST3, BND) do { \
    bf16x8 a00, a10, a20, a30, a01, a11, a21, a31; \
    bf16x8 b00, b10, b01, b11, c00, c10, c01, c11; \
    READ_A(S, 0); READ_B(S, 0, b00, b10, b01, b11); \
    ST0; PH_PRE; MFMA16(0, 0, b00, b10, b01, b11); PH_POST; \
    READ_A(S, 1); \
    ST1; PH_PRE; MFMA16(1, 0, b00, b10, b01, b11); PH_POST; \
    READ_B(S, 1, c00, c10, c01, c11); \
    ST2; PH_PRE; MFMA16(1, 1, c00, c10, c01, c11); PH_POST; \
    READ_A(S, 0); \
    ST3; PH_PRE; MFMA16(0, 1, c00, c10, c01, c11); \
    __builtin_amdgcn_s_setprio(0); BND; BAR; \
} while (0)

__global__ __launch_bounds__(512, 2) void gemm8p_kernel(
    const ushort_t* __restrict__ Xb, const ushort_t* __restrict__ Wb,
    const float* __restrict__ bias, float* __restrict__ out) {
    extern __shared__ char lds[];

    const int tid   = threadIdx.x;
    const int lane  = tid & 63;
    const int wid   = tid >> 6;      // 0..7
    const int wm    = wid >> 2;      // 0..1  (M sub-block within each half)
    const int wn    = wid & 3;       // 0..3  (N sub-block within each half)
    const int fr    = lane & 15;
    const int khalf = lane >> 4;     // 0..3

    // T1: bijective XCD swizzle (512 % 8 == 0)
    const int orig  = blockIdx.x;
    const int wgid  = ((orig & 7) << 6) | (orig >> 3);
    const int ntile = wgid & 15;     // 16 N-tiles
    const int mtile = wgid >> 4;     // 32 M-tiles
    const int m0 = mtile << 8;
    const int n0 = ntile << 8;

    // stage addressing: granule g = l*512 + tid; LDS linear; global pre-swizzled
    const int g0 = tid, g1 = 512 + tid;
    const size_t goff0 = (size_t)(g0 >> 3) * NDIM + (size_t)((((g0 & 7) ^ ((g0 >> 3) & 7))) << 3);
    const size_t goff1 = (size_t)(g1 >> 3) * NDIM + (size_t)((((g1 & 7) ^ ((g1 >> 3) & 7))) << 3);
    const int ldsoff0 = (wid << 10);          // wave-uniform base, load 0
    const int ldsoff1 = 8192 + (wid << 10);   // load 1

    // fragment read offsets (bytes within a [128][64] bf16 half-buffer)
    const int rowA = ((wm << 6) + fr) << 7;               // (wm*64+fr)*128
    const int rowB = ((wn << 5) + fr) << 7;               // (wn*32+fr)*128
    const int cb0  = ((khalf)     ^ (fr & 7)) << 4;       // kk=0 chunk (swizzled)
    const int cb1  = ((4 + khalf) ^ (fr & 7)) << 4;       // kk=1 chunk

    f32x4 acc[8][4];
#pragma unroll
    for (int i = 0; i < 8; ++i)
#pragma unroll
        for (int j = 0; j < 4; ++j) { f32x4 z = {0.f,0.f,0.f,0.f}; acc[i][j] = z; }

    const ushort_t* Xrow0 = Xb + (size_t)m0 * NDIM;
    const ushort_t* Xrow1 = Xb + (size_t)(m0 + 128) * NDIM;
    const ushort_t* Wrow0 = Wb + (size_t)n0 * NDIM;
    const ushort_t* Wrow1 = Wb + (size_t)(n0 + 128) * NDIM;

    // Prologue: tile 0 complete (8 loads), then B0[1],A1[1],B1[1] (6 loads).
    // vmcnt(6) forces tile 0 landed; A0[1] is issued by tile 0's ph0 (steady rule).
    STAGE(lds + 0*LDS_SLOT + LDS_A0, Xrow0 + 0);
    STAGE(lds + 0*LDS_SLOT + LDS_B0, Wrow0 + 0);
    STAGE(lds + 0*LDS_SLOT + LDS_A1, Xrow1 + 0);
    STAGE(lds + 0*LDS_SLOT + LDS_B1, Wrow1 + 0);
    STAGE(lds + 1*LDS_SLOT + LDS_B0, Wrow0 + 64);
    STAGE(lds + 1*LDS_SLOT + LDS_A1, Xrow1 + 64);
    STAGE(lds + 1*LDS_SLOT + LDS_B1, Wrow1 + 64);
    VMCNT6;
    BAR;

    // Hot loop: tiles 0..61 (all stage guards statically true).
#pragma unroll 1
    for (int kt2 = 0; kt2 < NT / 2 - 1; ++kt2) {
        const int te = 2 * kt2, to = te + 1;
        TILE(0,
             STAGE(lds + 1*LDS_SLOT + LDS_A0, Xrow0 + (te + 1) * 64),
             STAGE(lds + 0*LDS_SLOT + LDS_B0, Wrow0 + (te + 2) * 64),
             STAGE(lds + 0*LDS_SLOT + LDS_A1, Xrow1 + (te + 2) * 64),
             STAGE(lds + 0*LDS_SLOT + LDS_B1, Wrow1 + (te + 2) * 64),
             VMCNT6);
        TILE(1,
             STAGE(lds + 0*LDS_SLOT + LDS_A0, Xrow0 + (to + 1) * 64),
             STAGE(lds + 1*LDS_SLOT + LDS_B0, Wrow0 + (to + 2) * 64),
             STAGE(lds + 1*LDS_SLOT + LDS_A1, Xrow1 + (to + 2) * 64),
             STAGE(lds + 1*LDS_SLOT + LDS_B1, Wrow1 + (to + 2) * 64),
             VMCNT6);
    }
    // Peeled tile 62 (slot 0): only A0[63] stage; vmcnt(0) at its boundary
    // (tail: <3 newer half-tiles exist, so the steady forcing argument breaks).
    TILE(0,
         STAGE(lds + 1*LDS_SLOT + LDS_A0, Xrow0 + 63 * 64),
         (void)0, (void)0, (void)0,
         VMCNT0);
    // Peeled tile 63 (slot 1): no stages, no boundary wait.
    TILE(1, (void)0, (void)0, (void)0, (void)0, (void)0);

    // Epilogue: C/D layout col=lane&15, row=(lane>>4)*4+reg.
    // row(i) = m0 + (i>>2)*128 + wm*64 + (i&3)*16 + khalf*4 + q
    // col(j) = n0 + (j>>1)*128 + wn*32 + (j&1)*16 + fr
    float bv[4];
#pragma unroll
    for (int j = 0; j < 4; ++j)
        bv[j] = bias[n0 + ((j >> 1) << 7) + (wn << 5) + ((j & 1) << 4) + fr];
#pragma unroll
    for (int i = 0; i < 8; ++i) {
        const int row = m0 + ((i >> 2) << 7) + (wm << 6) + ((i & 3) << 4) + (khalf << 2);
#pragma unroll
        for (int j = 0; j < 4; ++j) {
            const int col = n0 + ((j >> 1) << 7) + (wn << 5) + ((j & 1) << 4) + fr;
#pragma unroll
            for (int q = 0; q < 4; ++q)
                out[(size_t)(row + q) * KDIM + col] = acc[i][j][q] + bv[j];
        }
    }
}

// ---------------- Fallback (only if ws too small): naive fused ----------------
__global__ __launch_bounds__(256) void naive_kernel(
    const float* __restrict__ x, const int* __restrict__ Wq,
    const float* __restrict__ scales, const float* __restrict__ zeros,
    const int* __restrict__ mask, const float* __restrict__ scale2,
    const float* __restrict__ bias, float* __restrict__ out) {
    size_t o = (size_t)blockIdx.x * 256 + threadIdx.x;
    int m = (int)(o >> 12);
    int k = (int)(o & (KDIM - 1));
    const float* xr = x + (size_t)m * NDIM;
    const int* wr = Wq + (size_t)k * NDIM;
    const int* mr = mask + (size_t)k * NDIM;
    float s2 = scale2[k];
    float acc = 0.f;
    for (int g = 0; g < NGRP; ++g) {
        float ss = scales[k * NGRP + g] * s2;
        float z = zeros[k * NGRP + g];
        for (int n = g * GSZ; n < (g + 1) * GSZ; ++n)
            acc += xr[n] * (((float)wr[n] - z) * ss * (float)mr[n]);
    }
    out[o] = acc + bias[k];
}

extern "C" void kernel_launch(void* const* d_in, const int* in_sizes, int n_in,
                              void* d_out, int out_size, void* d_ws, size_t ws_size,
                              hipStream_t stream) {
    const float* x      = (const float*)d_in[0];
    const int*   Wq     = (const int*)d_in[1];
    const float* scales = (const float*)d_in[2];
    const float* zeros  = (const float*)d_in[3];
    const int*   mask   = (const int*)d_in[4];
    const float* scale2 = (const float*)d_in[5];
    const float* bias   = (const float*)d_in[6];
    float* out = (float*)d_out;

    const size_t needW = (size_t)KDIM * NDIM * sizeof(ushort_t);  // 32 MiB
    const size_t needX = (size_t)MDIM * NDIM * sizeof(ushort_t);  // 64 MiB

    if (ws_size >= needW + needX) {
        ushort_t* Wb = (ushort_t*)d_ws;
        ushort_t* Xb = (ushort_t*)((char*)d_ws + needW);
        hipLaunchKernelGGL(dq_w_kernel, dim3((KDIM * NDIM / 8) / 256), dim3(256),
                           0, stream, Wq, scales, zeros, mask, scale2, Wb);
        hipLaunchKernelGGL(cvt_x_kernel, dim3((MDIM * NDIM / 8) / 256), dim3(256),
                           0, stream, x, Xb);
        hipFuncSetAttribute((const void*)gemm8p_kernel,
                            hipFuncAttributeMaxDynamicSharedMemorySize, 131072);
        hipLaunchKernelGGL(gemm8p_kernel, dim3((MDIM / 256) * (KDIM / 256)), dim3(512),
                           131072, stream, Xb, Wb, bias, out);
    } else {
        hipLaunchKernelGGL(naive_kernel, dim3((MDIM * KDIM) / 256), dim3(256),
                           0, stream, x, Wq, scales, zeros, mask, scale2, bias, out);
    }
}

// Round 5
// 274.642 us; speedup vs baseline: 1.5932x; 1.0502x over previous
//
#include <hip/hip_runtime.h>
#include <hip/hip_bf16.h>
#include <cstdint>
#include <cstddef>

#define KDIM 4096   // out features
#define NDIM 4096   // in features (contraction dim)
#define NGRP 32
#define GSZ  128
#define MDIM 8192   // 4 * 2048 rows of x
#define NT   (NDIM / 64)   // 64 K-tiles of BK=64

typedef unsigned short ushort_t;
typedef float f32x4 __attribute__((ext_vector_type(4)));
typedef __bf16 bf16x8 __attribute__((ext_vector_type(8)));
typedef unsigned short u16x8 __attribute__((ext_vector_type(8)));
typedef int i32x4 __attribute__((ext_vector_type(4)));

// RTNE float -> bf16
__device__ __forceinline__ ushort_t f2bf(float f) {
    union { float f; unsigned u; } v; v.f = f;
    unsigned r = v.u + 0x7FFFu + ((v.u >> 16) & 1u);
    return (ushort_t)(r >> 16);
}

__device__ __forceinline__ void gload_lds16(const void* g, void* l) {
    __builtin_amdgcn_global_load_lds(
        (const __attribute__((address_space(1))) unsigned int*)g,
        (__attribute__((address_space(3))) unsigned int*)l,
        16, 0, 0);
}

// ---------------- Pass 1a: dequantize W -> bf16 [K, N] ----------------
__global__ __launch_bounds__(256) void dq_w_kernel(
    const int* __restrict__ Wq, const float* __restrict__ scales,
    const float* __restrict__ zeros, const int* __restrict__ mask,
    const float* __restrict__ scale2, ushort_t* __restrict__ Wb) {
    int gid = blockIdx.x * 256 + threadIdx.x;
    int e0 = gid * 8;
    int k = e0 >> 12;
    int n = e0 & (NDIM - 1);
    int g = n >> 7;
    float ss = scales[k * NGRP + g] * scale2[k];
    float z  = zeros[k * NGRP + g];
    i32x4 q0 = *(const i32x4*)(Wq + e0);
    i32x4 q1 = *(const i32x4*)(Wq + e0 + 4);
    i32x4 m0 = *(const i32x4*)(mask + e0);
    i32x4 m1 = *(const i32x4*)(mask + e0 + 4);
    u16x8 r;
#pragma unroll
    for (int i = 0; i < 4; ++i) r[i]     = f2bf(((float)q0[i] - z) * ss * (float)m0[i]);
#pragma unroll
    for (int i = 0; i < 4; ++i) r[4 + i] = f2bf(((float)q1[i] - z) * ss * (float)m1[i]);
    *(u16x8*)(Wb + e0) = r;
}

// ---------------- Pass 1b: convert x fp32 -> bf16 [M, N] ----------------
__global__ __launch_bounds__(256) void cvt_x_kernel(
    const float* __restrict__ x, ushort_t* __restrict__ Xb) {
    int gid = blockIdx.x * 256 + threadIdx.x;
    size_t e0 = (size_t)gid * 8;
    f32x4 a = *(const f32x4*)(x + e0);
    f32x4 b = *(const f32x4*)(x + e0 + 4);
    u16x8 r;
#pragma unroll
    for (int i = 0; i < 4; ++i) r[i] = f2bf(a[i]);
#pragma unroll
    for (int i = 0; i < 4; ++i) r[4 + i] = f2bf(b[i]);
    *(u16x8*)(Xb + e0) = r;
}

// ---------------- Pass 2: 256x256-tile bf16 GEMM, 4-barrier tiles --------
// out[m][k] = sum_n Xb[m][n] * Wb[k][n] + bias[k]
// 512 threads = 8 waves (2M x 4N). BK=64. LDS: 2 slots x {A0,A1,B0,B1}
// halves of [128][64] bf16 (16 KB each) = 128 KiB.
// Cluster order (A0,B0)->(A0,B1)->(A1,B1)->(A1,B0): A0 kept in a-regs for
// the first two clusters, A1 loaded AFTER cluster (0,1) retires (round-4 bug:
// loading A1 before (0,1) clobbered the a-regs -> wrong acc rows). B0/B1
// cached in b/c regs across the tile. 24 ds_read_b128/tile/wave (minimum).
// 4 barriers/tile (one per 16-MFMA cluster). Overwrite-safety chain:
//   ST1 (B0[t+2]->S) after BAR0: b-reads drained before MFMA(0,0) < BAR0.
//   ST2 (B1[t+2]->S) after BAR1: c-reads drained before MFMA(0,1) < BAR1.
//   ST3 (A1[t+2]->S) after BAR2: A1-reads drained before MFMA(1,1) < BAR2.
//   ST0 (A0[t+1]->S^1) after tile-end BAR: A0[S^1] last read >=3 bars ago.
// (lgkmcnt retires in order, so draining a later read drains earlier ones.)
// vmcnt(6) before each tile-end barrier: forced set = exactly tile t+1's
// halves (A0 staged 1 tile ahead, B0/B1/A1 two tiles ahead = 6 in flight).
// vmcnt(0) at the tile-62 boundary (tail); tiles 62/63 peeled.

#define LDS_SLOT 65536
#define LDS_A0   0
#define LDS_A1   16384
#define LDS_B0   32768
#define LDS_B1   49152

#define STAGE(ldsHalf, gbase) do { \
    gload_lds16((gbase) + goff0, (ldsHalf) + ldsoff0); \
    gload_lds16((gbase) + goff1, (ldsHalf) + ldsoff1); } while (0)

#define READ_A(S, QM) do { \
    const char* Ab_ = lds + (S)*LDS_SLOT + (QM)*16384 + rowA; \
    a00 = *(const bf16x8*)(Ab_ + 0*2048 + cb0); \
    a10 = *(const bf16x8*)(Ab_ + 1*2048 + cb0); \
    a20 = *(const bf16x8*)(Ab_ + 2*2048 + cb0); \
    a30 = *(const bf16x8*)(Ab_ + 3*2048 + cb0); \
    a01 = *(const bf16x8*)(Ab_ + 0*2048 + cb1); \
    a11 = *(const bf16x8*)(Ab_ + 1*2048 + cb1); \
    a21 = *(const bf16x8*)(Ab_ + 2*2048 + cb1); \
    a31 = *(const bf16x8*)(Ab_ + 3*2048 + cb1); \
} while (0)

#define READ_B(S, QN, B00, B10, B01, B11) do { \
    const char* Bb_ = lds + (S)*LDS_SLOT + 32768 + (QN)*16384 + rowB; \
    B00 = *(const bf16x8*)(Bb_ + 0*2048 + cb0); \
    B10 = *(const bf16x8*)(Bb_ + 1*2048 + cb0); \
    B01 = *(const bf16x8*)(Bb_ + 0*2048 + cb1); \
    B11 = *(const bf16x8*)(Bb_ + 1*2048 + cb1); \
} while (0)

#define MFMA16(QM, QN, B00, B10, B01, B11) do { \
    acc[(QM)*4+0][(QN)*2+0] = __builtin_amdgcn_mfma_f32_16x16x32_bf16(a00, B00, acc[(QM)*4+0][(QN)*2+0], 0,0,0); \
    acc[(QM)*4+1][(QN)*2+0] = __builtin_amdgcn_mfma_f32_16x16x32_bf16(a10, B00, acc[(QM)*4+1][(QN)*2+0], 0,0,0); \
    acc[(QM)*4+2][(QN)*2+0] = __builtin_amdgcn_mfma_f32_16x16x32_bf16(a20, B00, acc[(QM)*4+2][(QN)*2+0], 0,0,0); \
    acc[(QM)*4+3][(QN)*2+0] = __builtin_amdgcn_mfma_f32_16x16x32_bf16(a30, B00, acc[(QM)*4+3][(QN)*2+0], 0,0,0); \
    acc[(QM)*4+0][(QN)*2+1] = __builtin_amdgcn_mfma_f32_16x16x32_bf16(a00, B10, acc[(QM)*4+0][(QN)*2+1], 0,0,0); \
    acc[(QM)*4+1][(QN)*2+1] = __builtin_amdgcn_mfma_f32_16x16x32_bf16(a10, B10, acc[(QM)*4+1][(QN)*2+1], 0,0,0); \
    acc[(QM)*4+2][(QN)*2+1] = __builtin_amdgcn_mfma_f32_16x16x32_bf16(a20, B10, acc[(QM)*4+2][(QN)*2+1], 0,0,0); \
    acc[(QM)*4+3][(QN)*2+1] = __builtin_amdgcn_mfma_f32_16x16x32_bf16(a30, B10, acc[(QM)*4+3][(QN)*2+1], 0,0,0); \
    acc[(QM)*4+0][(QN)*2+0] = __builtin_amdgcn_mfma_f32_16x16x32_bf16(a01, B01, acc[(QM)*4+0][(QN)*2+0], 0,0,0); \
    acc[(QM)*4+1][(QN)*2+0] = __builtin_amdgcn_mfma_f32_16x16x32_bf16(a11, B01, acc[(QM)*4+1][(QN)*2+0], 0,0,0); \
    acc[(QM)*4+2][(QN)*2+0] = __builtin_amdgcn_mfma_f32_16x16x32_bf16(a21, B01, acc[(QM)*4+2][(QN)*2+0], 0,0,0); \
    acc[(QM)*4+3][(QN)*2+0] = __builtin_amdgcn_mfma_f32_16x16x32_bf16(a31, B01, acc[(QM)*4+3][(QN)*2+0], 0,0,0); \
    acc[(QM)*4+0][(QN)*2+1] = __builtin_amdgcn_mfma_f32_16x16x32_bf16(a01, B11, acc[(QM)*4+0][(QN)*2+1], 0,0,0); \
    acc[(QM)*4+1][(QN)*2+1] = __builtin_amdgcn_mfma_f32_16x16x32_bf16(a11, B11, acc[(QM)*4+1][(QN)*2+1], 0,0,0); \
    acc[(QM)*4+2][(QN)*2+1] = __builtin_amdgcn_mfma_f32_16x16x32_bf16(a21, B11, acc[(QM)*4+2][(QN)*2+1], 0,0,0); \
    acc[(QM)*4+3][(QN)*2+1] = __builtin_amdgcn_mfma_f32_16x16x32_bf16(a31, B11, acc[(QM)*4+3][(QN)*2+1], 0,0,0); \
} while (0)

#define BAR    asm volatile("s_barrier" ::: "memory")
#define VMCNT6 asm volatile("s_waitcnt vmcnt(6)" ::: "memory")
#define VMCNT0 asm volatile("s_waitcnt vmcnt(0)" ::: "memory")
#define SB     __builtin_amdgcn_sched_barrier(0)

#define CLUSTER(QM, QN, B00, B10, B01, B11) do { \
    SB; __builtin_amdgcn_s_setprio(1); \
    MFMA16(QM, QN, B00, B10, B01, B11); \
    __builtin_amdgcn_s_setprio(0); SB; \
} while (0)

// One K-tile: 4 MFMA clusters, 4 barriers. BND before the tile-end barrier.
// A1 is loaded only AFTER cluster (0,1) has consumed the A0 a-regs.
#define TILE(S, ST0, ST1, ST2, ST3, BND) do { \
    bf16x8 a00, a10, a20, a30, a01, a11, a21, a31; \
    bf16x8 b00, b10, b01, b11, c00, c10, c01, c11; \
    READ_A(S, 0); READ_B(S, 0, b00, b10, b01, b11); READ_B(S, 1, c00, c10, c01, c11); \
    ST0; \
    CLUSTER(0, 0, b00, b10, b01, b11); \
    BAR; \
    ST1; \
    CLUSTER(0, 1, c00, c10, c01, c11); \
    BAR; \
    READ_A(S, 1); \
    ST2; \
    CLUSTER(1, 1, c00, c10, c01, c11); \
    BAR; \
    ST3; \
    CLUSTER(1, 0, b00, b10, b01, b11); \
    BND; BAR; \
} while (0)

__global__ __launch_bounds__(512, 2) void gemm8p_kernel(
    const ushort_t* __restrict__ Xb, const ushort_t* __restrict__ Wb,
    const float* __restrict__ bias, float* __restrict__ out) {
    extern __shared__ char lds[];

    const int tid   = threadIdx.x;
    const int lane  = tid & 63;
    const int wid   = tid >> 6;      // 0..7
    const int wm    = wid >> 2;      // 0..1  (M sub-block within each half)
    const int wn    = wid & 3;       // 0..3  (N sub-block within each half)
    const int fr    = lane & 15;
    const int khalf = lane >> 4;     // 0..3

    // T1: bijective XCD swizzle (512 % 8 == 0)
    const int orig  = blockIdx.x;
    const int wgid  = ((orig & 7) << 6) | (orig >> 3);
    const int ntile = wgid & 15;     // 16 N-tiles
    const int mtile = wgid >> 4;     // 32 M-tiles
    const int m0 = mtile << 8;
    const int n0 = ntile << 8;

    // stage addressing: granule g = l*512 + tid; LDS linear; global pre-swizzled
    const int g0 = tid, g1 = 512 + tid;
    const size_t goff0 = (size_t)(g0 >> 3) * NDIM + (size_t)((((g0 & 7) ^ ((g0 >> 3) & 7))) << 3);
    const size_t goff1 = (size_t)(g1 >> 3) * NDIM + (size_t)((((g1 & 7) ^ ((g1 >> 3) & 7))) << 3);
    const int ldsoff0 = (wid << 10);          // wave-uniform base, load 0
    const int ldsoff1 = 8192 + (wid << 10);   // load 1

    // fragment read offsets (bytes within a [128][64] bf16 half-buffer)
    const int rowA = ((wm << 6) + fr) << 7;               // (wm*64+fr)*128
    const int rowB = ((wn << 5) + fr) << 7;               // (wn*32+fr)*128
    const int cb0  = ((khalf)     ^ (fr & 7)) << 4;       // kk=0 chunk (swizzled)
    const int cb1  = ((4 + khalf) ^ (fr & 7)) << 4;       // kk=1 chunk

    f32x4 acc[8][4];
#pragma unroll
    for (int i = 0; i < 8; ++i)
#pragma unroll
        for (int j = 0; j < 4; ++j) { f32x4 z = {0.f,0.f,0.f,0.f}; acc[i][j] = z; }

    const ushort_t* Xrow0 = Xb + (size_t)m0 * NDIM;
    const ushort_t* Xrow1 = Xb + (size_t)(m0 + 128) * NDIM;
    const ushort_t* Wrow0 = Wb + (size_t)n0 * NDIM;
    const ushort_t* Wrow1 = Wb + (size_t)(n0 + 128) * NDIM;

    // Prologue: tile 0 complete into slot 0 (8 loads), then B0[1],B1[1],A1[1]
    // into slot 1 (6 loads). vmcnt(6) forces tile 0 landed; A0[1] staged at
    // tile 0's ST0 (steady rule).
    STAGE(lds + 0*LDS_SLOT + LDS_A0, Xrow0 + 0);
    STAGE(lds + 0*LDS_SLOT + LDS_B0, Wrow0 + 0);
    STAGE(lds + 0*LDS_SLOT + LDS_B1, Wrow1 + 0);
    STAGE(lds + 0*LDS_SLOT + LDS_A1, Xrow1 + 0);
    STAGE(lds + 1*LDS_SLOT + LDS_B0, Wrow0 + 64);
    STAGE(lds + 1*LDS_SLOT + LDS_B1, Wrow1 + 64);
    STAGE(lds + 1*LDS_SLOT + LDS_A1, Xrow1 + 64);
    VMCNT6;
    BAR;

    // Hot loop: tiles 0..61 (all stage indices statically valid).
#pragma unroll 1
    for (int kt2 = 0; kt2 < NT / 2 - 1; ++kt2) {
        const int te = 2 * kt2, to = te + 1;
        TILE(0,
             STAGE(lds + 1*LDS_SLOT + LDS_A0, Xrow0 + (te + 1) * 64),
             STAGE(lds + 0*LDS_SLOT + LDS_B0, Wrow0 + (te + 2) * 64),
             STAGE(lds + 0*LDS_SLOT + LDS_B1, Wrow1 + (te + 2) * 64),
             STAGE(lds + 0*LDS_SLOT + LDS_A1, Xrow1 + (te + 2) * 64),
             VMCNT6);
        TILE(1,
             STAGE(lds + 0*LDS_SLOT + LDS_A0, Xrow0 + (to + 1) * 64),
             STAGE(lds + 1*LDS_SLOT + LDS_B0, Wrow0 + (to + 2) * 64),
             STAGE(lds + 1*LDS_SLOT + LDS_B1, Wrow1 + (to + 2) * 64),
             STAGE(lds + 1*LDS_SLOT + LDS_A1, Xrow1 + (to + 2) * 64),
             VMCNT6);
    }
    // Peeled tile 62 (slot 0): only A0[63]; vmcnt(0) at its boundary (tail:
    // fewer than 3 newer half-tiles exist, steady forcing breaks).
    TILE(0,
         STAGE(lds + 1*LDS_SLOT + LDS_A0, Xrow0 + 63 * 64),
         (void)0, (void)0, (void)0,
         VMCNT0);
    // Peeled tile 63 (slot 1): no stages, no boundary wait.
    TILE(1, (void)0, (void)0, (void)0, (void)0, (void)0);

    // Epilogue: C/D layout col=lane&15, row=(lane>>4)*4+reg.
    // row(i) = m0 + (i>>2)*128 + wm*64 + (i&3)*16 + khalf*4 + q
    // col(j) = n0 + (j>>1)*128 + wn*32 + (j&1)*16 + fr
    float bv[4];
#pragma unroll
    for (int j = 0; j < 4; ++j)
        bv[j] = bias[n0 + ((j >> 1) << 7) + (wn << 5) + ((j & 1) << 4) + fr];
#pragma unroll
    for (int i = 0; i < 8; ++i) {
        const int row = m0 + ((i >> 2) << 7) + (wm << 6) + ((i & 3) << 4) + (khalf << 2);
#pragma unroll
        for (int j = 0; j < 4; ++j) {
            const int col = n0 + ((j >> 1) << 7) + (wn << 5) + ((j & 1) << 4) + fr;
#pragma unroll
            for (int q = 0; q < 4; ++q)
                out[(size_t)(row + q) * KDIM + col] = acc[i][j][q] + bv[j];
        }
    }
}

// ---------------- Fallback (only if ws too small): naive fused ----------------
__global__ __launch_bounds__(256) void naive_kernel(
    const float* __restrict__ x, const int* __restrict__ Wq,
    const float* __restrict__ scales, const float* __restrict__ zeros,
    const int* __restrict__ mask, const float* __restrict__ scale2,
    const float* __restrict__ bias, float* __restrict__ out) {
    size_t o = (size_t)blockIdx.x * 256 + threadIdx.x;
    int m = (int)(o >> 12);
    int k = (int)(o & (KDIM - 1));
    const float* xr = x + (size_t)m * NDIM;
    const int* wr = Wq + (size_t)k * NDIM;
    const int* mr = mask + (size_t)k * NDIM;
    float s2 = scale2[k];
    float acc = 0.f;
    for (int g = 0; g < NGRP; ++g) {
        float ss = scales[k * NGRP + g] * s2;
        float z = zeros[k * NGRP + g];
        for (int n = g * GSZ; n < (g + 1) * GSZ; ++n)
            acc += xr[n] * (((float)wr[n] - z) * ss * (float)mr[n]);
    }
    out[o] = acc + bias[k];
}

extern "C" void kernel_launch(void* const* d_in, const int* in_sizes, int n_in,
                              void* d_out, int out_size, void* d_ws, size_t ws_size,
                              hipStream_t stream) {
    const float* x      = (const float*)d_in[0];
    const int*   Wq     = (const int*)d_in[1];
    const float* scales = (const float*)d_in[2];
    const float* zeros  = (const float*)d_in[3];
    const int*   mask   = (const int*)d_in[4];
    const float* scale2 = (const float*)d_in[5];
    const float* bias   = (const float*)d_in[6];
    float* out = (float*)d_out;

    const size_t needW = (size_t)KDIM * NDIM * sizeof(ushort_t);  // 32 MiB
    const size_t needX = (size_t)MDIM * NDIM * sizeof(ushort_t);  // 64 MiB

    if (ws_size >= needW + needX) {
        ushort_t* Wb = (ushort_t*)d_ws;
        ushort_t* Xb = (ushort_t*)((char*)d_ws + needW);
        hipLaunchKernelGGL(dq_w_kernel, dim3((KDIM * NDIM / 8) / 256), dim3(256),
                           0, stream, Wq, scales, zeros, mask, scale2, Wb);
        hipLaunchKernelGGL(cvt_x_kernel, dim3((MDIM * NDIM / 8) / 256), dim3(256),
                           0, stream, x, Xb);
        hipFuncSetAttribute((const void*)gemm8p_kernel,
                            hipFuncAttributeMaxDynamicSharedMemorySize, 131072);
        hipLaunchKernelGGL(gemm8p_kernel, dim3((MDIM / 256) * (KDIM / 256)), dim3(512),
                           131072, stream, Xb, Wb, bias, out);
    } else {
        hipLaunchKernelGGL(naive_kernel, dim3((MDIM * KDIM) / 256), dim3(256),
                           0, stream, x, Wq, scales, zeros, mask, scale2, bias, out);
    }
}

// Round 6
// 271.418 us; speedup vs baseline: 1.6121x; 1.0119x over previous
//
#include <hip/hip_runtime.h>
#include <hip/hip_bf16.h>
#include <cstdint>
#include <cstddef>

#define KDIM 4096   // out features
#define NDIM 4096   // in features (contraction dim)
#define NGRP 32
#define GSZ  128
#define MDIM 8192   // 4 * 2048 rows of x
#define NT   (NDIM / 64)   // 64 K-tiles of BK=64

typedef unsigned short ushort_t;
typedef float f32x4 __attribute__((ext_vector_type(4)));
typedef __bf16 bf16x8 __attribute__((ext_vector_type(8)));
typedef unsigned short u16x8 __attribute__((ext_vector_type(8)));
typedef int i32x4 __attribute__((ext_vector_type(4)));

// RTNE float -> bf16
__device__ __forceinline__ ushort_t f2bf(float f) {
    union { float f; unsigned u; } v; v.f = f;
    unsigned r = v.u + 0x7FFFu + ((v.u >> 16) & 1u);
    return (ushort_t)(r >> 16);
}

__device__ __forceinline__ void gload_lds16(const void* g, void* l) {
    __builtin_amdgcn_global_load_lds(
        (const __attribute__((address_space(1))) unsigned int*)g,
        (__attribute__((address_space(3))) unsigned int*)l,
        16, 0, 0);
}

// ---------------- Pass 1a: dequantize W -> bf16 [K, N] ----------------
__global__ __launch_bounds__(256) void dq_w_kernel(
    const int* __restrict__ Wq, const float* __restrict__ scales,
    const float* __restrict__ zeros, const int* __restrict__ mask,
    const float* __restrict__ scale2, ushort_t* __restrict__ Wb) {
    int gid = blockIdx.x * 256 + threadIdx.x;
    int e0 = gid * 8;
    int k = e0 >> 12;
    int n = e0 & (NDIM - 1);
    int g = n >> 7;
    float ss = scales[k * NGRP + g] * scale2[k];
    float z  = zeros[k * NGRP + g];
    i32x4 q0 = *(const i32x4*)(Wq + e0);
    i32x4 q1 = *(const i32x4*)(Wq + e0 + 4);
    i32x4 m0 = *(const i32x4*)(mask + e0);
    i32x4 m1 = *(const i32x4*)(mask + e0 + 4);
    u16x8 r;
#pragma unroll
    for (int i = 0; i < 4; ++i) r[i]     = f2bf(((float)q0[i] - z) * ss * (float)m0[i]);
#pragma unroll
    for (int i = 0; i < 4; ++i) r[4 + i] = f2bf(((float)q1[i] - z) * ss * (float)m1[i]);
    *(u16x8*)(Wb + e0) = r;
}

// ---------------- Pass 1b: convert x fp32 -> bf16 [M, N] ----------------
__global__ __launch_bounds__(256) void cvt_x_kernel(
    const float* __restrict__ x, ushort_t* __restrict__ Xb) {
    int gid = blockIdx.x * 256 + threadIdx.x;
    size_t e0 = (size_t)gid * 8;
    f32x4 a = *(const f32x4*)(x + e0);
    f32x4 b = *(const f32x4*)(x + e0 + 4);
    u16x8 r;
#pragma unroll
    for (int i = 0; i < 4; ++i) r[i] = f2bf(a[i]);
#pragma unroll
    for (int i = 0; i < 4; ++i) r[4 + i] = f2bf(b[i]);
    *(u16x8*)(Xb + e0) = r;
}

// ---------------- Pass 2: 256x256-tile bf16 GEMM, read-pipelined --------
// out[m][k] = sum_n Xb[m][n] * Wb[k][n] + bias[k]
// 512 threads = 8 waves (2M x 4N). BK=64. LDS: 2 slots x {A0,A1,B0,B1}
// halves of [128][64] bf16 (16 KB each) = 128 KiB.
// Cluster order (0,0)->(0,1)->(1,1)->(1,0). EVERY ds_read overlaps a prior
// MFMA cluster (zero extra registers; B0/B1 reg roles alternate per tile):
//   B1[t]   read after (0,0) issues  (consumed by (0,1))
//   A1[t]   read after (0,1) issues  (a-regs WAR-free; consumed by (1,1))
//   B0[t+1] read after BAR3          (into dead B1-regs; consumed by t+1 (0,0))
//   A0[t+1] read after (1,0) issues  (a-regs WAR-free; consumed by t+1 (0,0))
// VMCNT6 moved to right after ST3 (before BAR3): forced set unchanged =
// oldest 8 = exactly tile t+1's halves (issued >=1 tile ago, landed free).
// Overwrite-safety (all reads retire via data-dep before the cluster that
// consumes them, which precedes the barrier that precedes the overwrite):
//   ST1 (B0[t+2]->S) after BAR0: B0[t] reads retired before (0,0) < BAR0.
//   ST2 (B1[t+2]->S) after BAR1: B1[t] reads retired before (0,1) < BAR1.
//   ST3 (A1[t+2]->S) after BAR2: A1[t] reads retired before (1,1) < BAR2.
//   ST0 (A0[t+1]->S^1) at tile start: A0[t-1] reads retired in tile t-1.
//   Pre-reads of B0[t+1]/A0[t+1] (slot S^1): next overwrite of those regions
//   is t+1's ST1 (B0[t+3], after t+1's BAR0 > consumption) / t+2's ST0.
// vmcnt ledger identical to round-5-proven scheme; vmcnt(0) at tile 62.

#define LDS_SLOT 65536
#define LDS_A0   0
#define LDS_A1   16384
#define LDS_B0   32768
#define LDS_B1   49152

#define STAGE(ldsHalf, gbase) do { \
    gload_lds16((gbase) + goff0, (ldsHalf) + ldsoff0); \
    gload_lds16((gbase) + goff1, (ldsHalf) + ldsoff1); } while (0)

#define READ_A(S, QM) do { \
    const char* Ab_ = lds + (S)*LDS_SLOT + (QM)*16384 + rowA; \
    a00 = *(const bf16x8*)(Ab_ + 0*2048 + cb0); \
    a10 = *(const bf16x8*)(Ab_ + 1*2048 + cb0); \
    a20 = *(const bf16x8*)(Ab_ + 2*2048 + cb0); \
    a30 = *(const bf16x8*)(Ab_ + 3*2048 + cb0); \
    a01 = *(const bf16x8*)(Ab_ + 0*2048 + cb1); \
    a11 = *(const bf16x8*)(Ab_ + 1*2048 + cb1); \
    a21 = *(const bf16x8*)(Ab_ + 2*2048 + cb1); \
    a31 = *(const bf16x8*)(Ab_ + 3*2048 + cb1); \
} while (0)

#define READ_B(S, QN, B00, B10, B01, B11) do { \
    const char* Bb_ = lds + (S)*LDS_SLOT + 32768 + (QN)*16384 + rowB; \
    B00 = *(const bf16x8*)(Bb_ + 0*2048 + cb0); \
    B10 = *(const bf16x8*)(Bb_ + 1*2048 + cb0); \
    B01 = *(const bf16x8*)(Bb_ + 0*2048 + cb1); \
    B11 = *(const bf16x8*)(Bb_ + 1*2048 + cb1); \
} while (0)

#define MFMA16(QM, QN, B00, B10, B01, B11) do { \
    acc[(QM)*4+0][(QN)*2+0] = __builtin_amdgcn_mfma_f32_16x16x32_bf16(a00, B00, acc[(QM)*4+0][(QN)*2+0], 0,0,0); \
    acc[(QM)*4+1][(QN)*2+0] = __builtin_amdgcn_mfma_f32_16x16x32_bf16(a10, B00, acc[(QM)*4+1][(QN)*2+0], 0,0,0); \
    acc[(QM)*4+2][(QN)*2+0] = __builtin_amdgcn_mfma_f32_16x16x32_bf16(a20, B00, acc[(QM)*4+2][(QN)*2+0], 0,0,0); \
    acc[(QM)*4+3][(QN)*2+0] = __builtin_amdgcn_mfma_f32_16x16x32_bf16(a30, B00, acc[(QM)*4+3][(QN)*2+0], 0,0,0); \
    acc[(QM)*4+0][(QN)*2+1] = __builtin_amdgcn_mfma_f32_16x16x32_bf16(a00, B10, acc[(QM)*4+0][(QN)*2+1], 0,0,0); \
    acc[(QM)*4+1][(QN)*2+1] = __builtin_amdgcn_mfma_f32_16x16x32_bf16(a10, B10, acc[(QM)*4+1][(QN)*2+1], 0,0,0); \
    acc[(QM)*4+2][(QN)*2+1] = __builtin_amdgcn_mfma_f32_16x16x32_bf16(a20, B10, acc[(QM)*4+2][(QN)*2+1], 0,0,0); \
    acc[(QM)*4+3][(QN)*2+1] = __builtin_amdgcn_mfma_f32_16x16x32_bf16(a30, B10, acc[(QM)*4+3][(QN)*2+1], 0,0,0); \
    acc[(QM)*4+0][(QN)*2+0] = __builtin_amdgcn_mfma_f32_16x16x32_bf16(a01, B01, acc[(QM)*4+0][(QN)*2+0], 0,0,0); \
    acc[(QM)*4+1][(QN)*2+0] = __builtin_amdgcn_mfma_f32_16x16x32_bf16(a11, B01, acc[(QM)*4+1][(QN)*2+0], 0,0,0); \
    acc[(QM)*4+2][(QN)*2+0] = __builtin_amdgcn_mfma_f32_16x16x32_bf16(a21, B01, acc[(QM)*4+2][(QN)*2+0], 0,0,0); \
    acc[(QM)*4+3][(QN)*2+0] = __builtin_amdgcn_mfma_f32_16x16x32_bf16(a31, B01, acc[(QM)*4+3][(QN)*2+0], 0,0,0); \
    acc[(QM)*4+0][(QN)*2+1] = __builtin_amdgcn_mfma_f32_16x16x32_bf16(a01, B11, acc[(QM)*4+0][(QN)*2+1], 0,0,0); \
    acc[(QM)*4+1][(QN)*2+1] = __builtin_amdgcn_mfma_f32_16x16x32_bf16(a11, B11, acc[(QM)*4+1][(QN)*2+1], 0,0,0); \
    acc[(QM)*4+2][(QN)*2+1] = __builtin_amdgcn_mfma_f32_16x16x32_bf16(a21, B11, acc[(QM)*4+2][(QN)*2+1], 0,0,0); \
    acc[(QM)*4+3][(QN)*2+1] = __builtin_amdgcn_mfma_f32_16x16x32_bf16(a31, B11, acc[(QM)*4+3][(QN)*2+1], 0,0,0); \
} while (0)

#define BAR    asm volatile("s_barrier" ::: "memory")
#define VMCNT6 asm volatile("s_waitcnt vmcnt(6)" ::: "memory")
#define VMCNT0 asm volatile("s_waitcnt vmcnt(0)" ::: "memory")
#define SB     __builtin_amdgcn_sched_barrier(0)

#define CLUSTER(QM, QN, B00, B10, B01, B11) do { \
    SB; __builtin_amdgcn_s_setprio(1); \
    MFMA16(QM, QN, B00, B10, B01, B11); \
    __builtin_amdgcn_s_setprio(0); SB; \
} while (0)

// One K-tile. Entry state: a = A0[t], P = B0[t]. Exit: a = A0[t+1],
// Q = B0[t+1] (P/Q roles swap each tile). Pre-reads for peeled last tile
// are dead and DCE'd.
#define TILE2(S, P00,P10,P01,P11, Q00,Q10,Q01,Q11, ST0, ST1, ST2, ST3, BND) do { \
    ST0; \
    CLUSTER(0, 0, P00,P10,P01,P11); \
    READ_B(S, 1, Q00,Q10,Q01,Q11); \
    BAR; \
    ST1; \
    CLUSTER(0, 1, Q00,Q10,Q01,Q11); \
    READ_A(S, 1); \
    BAR; \
    ST2; \
    CLUSTER(1, 1, Q00,Q10,Q01,Q11); \
    BAR; \
    ST3; \
    BND; \
    BAR; \
    READ_B((S)^1, 0, Q00,Q10,Q01,Q11); \
    CLUSTER(1, 0, P00,P10,P01,P11); \
    READ_A((S)^1, 0); \
} while (0)

__global__ __launch_bounds__(512, 2) void gemm8p_kernel(
    const ushort_t* __restrict__ Xb, const ushort_t* __restrict__ Wb,
    const float* __restrict__ bias, float* __restrict__ out) {
    extern __shared__ char lds[];

    const int tid   = threadIdx.x;
    const int lane  = tid & 63;
    const int wid   = tid >> 6;      // 0..7
    const int wm    = wid >> 2;      // 0..1  (M sub-block within each half)
    const int wn    = wid & 3;       // 0..3  (N sub-block within each half)
    const int fr    = lane & 15;
    const int khalf = lane >> 4;     // 0..3

    // T1: bijective XCD swizzle (512 % 8 == 0)
    const int orig  = blockIdx.x;
    const int wgid  = ((orig & 7) << 6) | (orig >> 3);
    const int ntile = wgid & 15;     // 16 N-tiles
    const int mtile = wgid >> 4;     // 32 M-tiles
    const int m0 = mtile << 8;
    const int n0 = ntile << 8;

    // stage addressing: granule g = l*512 + tid; LDS linear; global pre-swizzled
    const int g0 = tid, g1 = 512 + tid;
    const size_t goff0 = (size_t)(g0 >> 3) * NDIM + (size_t)((((g0 & 7) ^ ((g0 >> 3) & 7))) << 3);
    const size_t goff1 = (size_t)(g1 >> 3) * NDIM + (size_t)((((g1 & 7) ^ ((g1 >> 3) & 7))) << 3);
    const int ldsoff0 = (wid << 10);          // wave-uniform base, load 0
    const int ldsoff1 = 8192 + (wid << 10);   // load 1

    // fragment read offsets (bytes within a [128][64] bf16 half-buffer)
    const int rowA = ((wm << 6) + fr) << 7;               // (wm*64+fr)*128
    const int rowB = ((wn << 5) + fr) << 7;               // (wn*32+fr)*128
    const int cb0  = ((khalf)     ^ (fr & 7)) << 4;       // kk=0 chunk (swizzled)
    const int cb1  = ((4 + khalf) ^ (fr & 7)) << 4;       // kk=1 chunk

    f32x4 acc[8][4];
#pragma unroll
    for (int i = 0; i < 8; ++i)
#pragma unroll
        for (int j = 0; j < 4; ++j) { f32x4 z = {0.f,0.f,0.f,0.f}; acc[i][j] = z; }

    const ushort_t* Xrow0 = Xb + (size_t)m0 * NDIM;
    const ushort_t* Xrow1 = Xb + (size_t)(m0 + 128) * NDIM;
    const ushort_t* Wrow0 = Wb + (size_t)n0 * NDIM;
    const ushort_t* Wrow1 = Wb + (size_t)(n0 + 128) * NDIM;

    // fragment registers: a = current A-half; p/q = B0/B1 (roles alternate)
    bf16x8 a00, a10, a20, a30, a01, a11, a21, a31;
    bf16x8 p00, p10, p01, p11, q00, q10, q01, q11;

    // Prologue: tile 0 complete into slot 0 (8 loads), then B0[1],B1[1],A1[1]
    // into slot 1 (6 loads). vmcnt(6) forces tile 0 landed. Then read tile 0's
    // (0,0)-operands (one-time startup drain).
    STAGE(lds + 0*LDS_SLOT + LDS_A0, Xrow0 + 0);
    STAGE(lds + 0*LDS_SLOT + LDS_B0, Wrow0 + 0);
    STAGE(lds + 0*LDS_SLOT + LDS_B1, Wrow1 + 0);
    STAGE(lds + 0*LDS_SLOT + LDS_A1, Xrow1 + 0);
    STAGE(lds + 1*LDS_SLOT + LDS_B0, Wrow0 + 64);
    STAGE(lds + 1*LDS_SLOT + LDS_B1, Wrow1 + 64);
    STAGE(lds + 1*LDS_SLOT + LDS_A1, Xrow1 + 64);
    VMCNT6;
    BAR;
    READ_A(0, 0);
    READ_B(0, 0, p00, p10, p01, p11);

    // Hot loop: tiles 0..61 (all stage indices statically valid).
#pragma unroll 1
    for (int kt2 = 0; kt2 < NT / 2 - 1; ++kt2) {
        const int te = 2 * kt2, to = te + 1;
        TILE2(0, p00,p10,p01,p11, q00,q10,q01,q11,
              STAGE(lds + 1*LDS_SLOT + LDS_A0, Xrow0 + (te + 1) * 64),
              STAGE(lds + 0*LDS_SLOT + LDS_B0, Wrow0 + (te + 2) * 64),
              STAGE(lds + 0*LDS_SLOT + LDS_B1, Wrow1 + (te + 2) * 64),
              STAGE(lds + 0*LDS_SLOT + LDS_A1, Xrow1 + (te + 2) * 64),
              VMCNT6);
        TILE2(1, q00,q10,q01,q11, p00,p10,p01,p11,
              STAGE(lds + 0*LDS_SLOT + LDS_A0, Xrow0 + (to + 1) * 64),
              STAGE(lds + 1*LDS_SLOT + LDS_B0, Wrow0 + (to + 2) * 64),
              STAGE(lds + 1*LDS_SLOT + LDS_B1, Wrow1 + (to + 2) * 64),
              STAGE(lds + 1*LDS_SLOT + LDS_A1, Xrow1 + (to + 2) * 64),
              VMCNT6);
    }
    // Peeled tile 62 (slot 0): only A0[63] stage; vmcnt(0) at its boundary
    // (tail: steady forcing breaks). Its pre-reads fetch tile 63's operands.
    TILE2(0, p00,p10,p01,p11, q00,q10,q01,q11,
          STAGE(lds + 1*LDS_SLOT + LDS_A0, Xrow0 + 63 * 64),
          (void)0, (void)0, (void)0,
          VMCNT0);
    // Peeled tile 63 (slot 1): no stages; trailing pre-reads are dead (DCE).
    TILE2(1, q00,q10,q01,q11, p00,p10,p01,p11,
          (void)0, (void)0, (void)0, (void)0, (void)0);

    // Epilogue: C/D layout col=lane&15, row=(lane>>4)*4+reg.
    // row(i) = m0 + (i>>2)*128 + wm*64 + (i&3)*16 + khalf*4 + q
    // col(j) = n0 + (j>>1)*128 + wn*32 + (j&1)*16 + fr
    float bv[4];
#pragma unroll
    for (int j = 0; j < 4; ++j)
        bv[j] = bias[n0 + ((j >> 1) << 7) + (wn << 5) + ((j & 1) << 4) + fr];
#pragma unroll
    for (int i = 0; i < 8; ++i) {
        const int row = m0 + ((i >> 2) << 7) + (wm << 6) + ((i & 3) << 4) + (khalf << 2);
#pragma unroll
        for (int j = 0; j < 4; ++j) {
            const int col = n0 + ((j >> 1) << 7) + (wn << 5) + ((j & 1) << 4) + fr;
#pragma unroll
            for (int q = 0; q < 4; ++q)
                out[(size_t)(row + q) * KDIM + col] = acc[i][j][q] + bv[j];
        }
    }
}

// ---------------- Fallback (only if ws too small): naive fused ----------------
__global__ __launch_bounds__(256) void naive_kernel(
    const float* __restrict__ x, const int* __restrict__ Wq,
    const float* __restrict__ scales, const float* __restrict__ zeros,
    const int* __restrict__ mask, const float* __restrict__ scale2,
    const float* __restrict__ bias, float* __restrict__ out) {
    size_t o = (size_t)blockIdx.x * 256 + threadIdx.x;
    int m = (int)(o >> 12);
    int k = (int)(o & (KDIM - 1));
    const float* xr = x + (size_t)m * NDIM;
    const int* wr = Wq + (size_t)k * NDIM;
    const int* mr = mask + (size_t)k * NDIM;
    float s2 = scale2[k];
    float acc = 0.f;
    for (int g = 0; g < NGRP; ++g) {
        float ss = scales[k * NGRP + g] * s2;
        float z = zeros[k * NGRP + g];
        for (int n = g * GSZ; n < (g + 1) * GSZ; ++n)
            acc += xr[n] * (((float)wr[n] - z) * ss * (float)mr[n]);
    }
    out[o] = acc + bias[k];
}

extern "C" void kernel_launch(void* const* d_in, const int* in_sizes, int n_in,
                              void* d_out, int out_size, void* d_ws, size_t ws_size,
                              hipStream_t stream) {
    const float* x      = (const float*)d_in[0];
    const int*   Wq     = (const int*)d_in[1];
    const float* scales = (const float*)d_in[2];
    const float* zeros  = (const float*)d_in[3];
    const int*   mask   = (const int*)d_in[4];
    const float* scale2 = (const float*)d_in[5];
    const float* bias   = (const float*)d_in[6];
    float* out = (float*)d_out;

    const size_t needW = (size_t)KDIM * NDIM * sizeof(ushort_t);  // 32 MiB
    const size_t needX = (size_t)MDIM * NDIM * sizeof(ushort_t);  // 64 MiB

    if (ws_size >= needW + needX) {
        ushort_t* Wb = (ushort_t*)d_ws;
        ushort_t* Xb = (ushort_t*)((char*)d_ws + needW);
        hipLaunchKernelGGL(dq_w_kernel, dim3((KDIM * NDIM / 8) / 256), dim3(256),
                           0, stream, Wq, scales, zeros, mask, scale2, Wb);
        hipLaunchKernelGGL(cvt_x_kernel, dim3((MDIM * NDIM / 8) / 256), dim3(256),
                           0, stream, x, Xb);
        hipFuncSetAttribute((const void*)gemm8p_kernel,
                            hipFuncAttributeMaxDynamicSharedMemorySize, 131072);
        hipLaunchKernelGGL(gemm8p_kernel, dim3((MDIM / 256) * (KDIM / 256)), dim3(512),
                           131072, stream, Xb, Wb, bias, out);
    } else {
        hipLaunchKernelGGL(naive_kernel, dim3((MDIM * KDIM) / 256), dim3(256),
                           0, stream, x, Wq, scales, zeros, mask, scale2, bias, out);
    }
}